// Round 7
// baseline (24240.501 us; speedup 1.0000x reference)
//
#include <hip/hip_runtime.h>
#include <hip/hip_bf16.h>
#include <math.h>

// B=4, N=4096 -> 16384 windows of NHT=16 tokens, MD=128
#define NHT 16
#define MD 128
#define FFD 256
#define NHEAD 4
#define DH 32
#define PED 32
#define ED 64
#define SCALE 0.17677669529663687f
#define LDT 132      // float stride, scalar buffers
#define LDU 260      // float stride, scalar FFN hidden
#define LDQ 132      // float stride, MFMA-side natural rows
#define LDUS 36      // float stride, MFMA-side FFN u rows
#define SCRS 136     // short stride, bounce rows
#define TOL 0.02f

typedef __attribute__((ext_vector_type(8))) short bf8;
typedef __attribute__((ext_vector_type(4))) float f32x4;
union U8 { bf8 v; unsigned short s[8]; uint u[4]; uint4 q; };

#define MFMA __builtin_amdgcn_mfma_f32_16x16x32_bf16

__device__ __forceinline__ unsigned short bf1(float a){
  __hip_bfloat16 h = __float2bfloat16(a);
  return *reinterpret_cast<unsigned short*>(&h);
}
__device__ __forceinline__ float bfh2f(unsigned short s){
  __hip_bfloat16 h = *reinterpret_cast<__hip_bfloat16*>(&s);
  return __bfloat162float(h);
}
__device__ __forceinline__ void splits(float f, unsigned short &h, unsigned short &l){
  __hip_bfloat16 hb = __float2bfloat16(f);
  h = *reinterpret_cast<unsigned short*>(&hb);
  float r = f - __bfloat162float(hb);
  __hip_bfloat16 lb = __float2bfloat16(r);
  l = *reinterpret_cast<unsigned short*>(&lb);
}
__device__ __forceinline__ float silu_f(float x){ return x / (1.f + __expf(-x)); }

// butterfly LN on MFMA C-layout tile (lane: rows lg*4+r, cols nt*16+lm)
__device__ __forceinline__ void lnC(float (&C)[8][4], const float* __restrict__ g,
                                    const float* __restrict__ b, int lm){
#pragma unroll
  for (int r = 0; r < 4; ++r){
    float s = 0.f, ss = 0.f;
#pragma unroll
    for (int nt = 0; nt < 8; ++nt){ s += C[nt][r]; ss = fmaf(C[nt][r], C[nt][r], ss); }
#pragma unroll
    for (int m = 1; m < 16; m <<= 1){ s += __shfl_xor(s, m); ss += __shfl_xor(ss, m); }
    float mean = s * (1.f/128.f);
    float var  = ss * (1.f/128.f) - mean*mean;
    float rs   = rsqrtf(var + 1e-5f);
#pragma unroll
    for (int nt = 0; nt < 8; ++nt)
      C[nt][r] = fmaf((C[nt][r] - mean) * rs, g[nt*16+lm], b[nt*16+lm]);
  }
}

// serial per-row LN on scalar LDS tile [16][LDT] (threads 0..15)
__device__ __forceinline__ void ln_rows16(float* buf, const float* __restrict__ g,
                                          const float* __restrict__ b, int tid){
  if (tid < NHT){
    float* row = buf + tid * LDT;
    float s = 0.f, ss = 0.f;
#pragma unroll
    for (int i = 0; i < MD; ++i){ float v = row[i]; s += v; ss = fmaf(v, v, ss); }
    float m = s * (1.f/MD);
    float var = ss * (1.f/MD) - m*m;
    float r = rsqrtf(var + 1e-5f);
#pragma unroll
    for (int i = 0; i < MD; ++i) row[i] = fmaf((row[i]-m)*r, g[i], b[i]);
  }
}

// ---- weight pre-pack: fp32 [K][N] -> bf16 B-frag order, hi only; 256 KiB exact ----
__global__ __launch_bounds__(256)
void packw(const float* __restrict__ Wq, const float* __restrict__ Wk,
           const float* __restrict__ Wv, const float* __restrict__ Wo,
           const float* __restrict__ W1, const float* __restrict__ W2,
           uint4* __restrict__ ws){
  int id = blockIdx.x * 256 + threadIdx.x;   // 16384 total
  const float* W; int KT, N, u; uint4* dst;
  if      (id < 2048) { W = Wq;  KT = 4; N = 128; dst = ws;         u = id;         }
  else if (id < 4096) { W = Wk;  KT = 4; N = 128; dst = ws + 2048;  u = id - 2048;  }
  else if (id < 6144) { W = Wv;  KT = 4; N = 128; dst = ws + 4096;  u = id - 4096;  }
  else if (id < 8192) { W = Wo;  KT = 4; N = 128; dst = ws + 6144;  u = id - 6144;  }
  else if (id < 12288){ W = W1;  KT = 4; N = 256; dst = ws + 8192;  u = id - 8192;  }
  else                { W = W2;  KT = 8; N = 128; dst = ws + 12288; u = id - 12288; }
  int lane = u & 63, tile = u >> 6;
  int kt = tile % KT, nt = tile / KT;
  int kr  = kt*32 + ((lane >> 4) << 3);
  int col = nt*16 + (lane & 15);
  const float* p = W + (size_t)kr * N + col;
  U8 hi;
#pragma unroll
  for (int j = 0; j < 8; ++j) hi.s[j] = bf1(p[(size_t)j * N]);
  dst[u] = hi.q;
}

__global__ __launch_bounds__(64)
void nha_diag2(const float* __restrict__ x, const float* __restrict__ pos1,
               const float* __restrict__ pos2,
               const float* __restrict__ W_in,
               const float* __restrict__ g_in, const float* __restrict__ b_in,
               const float* __restrict__ W_pe, const float* __restrict__ W_bias,
               const float* __restrict__ Wq, const float* __restrict__ bq,
               const float* __restrict__ Wk, const float* __restrict__ bk,
               const float* __restrict__ Wv, const float* __restrict__ bv,
               const float* __restrict__ Wo, const float* __restrict__ bo,
               const float* __restrict__ W1, const float* __restrict__ W2,
               const float* __restrict__ g1, const float* __restrict__ b1,
               const float* __restrict__ g2, const float* __restrict__ b2,
               const uint4* __restrict__ wsp, float* __restrict__ out)
{
  const uint4* pWq  = wsp;
  const uint4* pWk  = wsp + 2048;
  const uint4* pWv  = wsp + 4096;
  const uint4* pWo  = wsp + 6144;
  const uint4* pW1  = wsp + 8192;
  const uint4* pW2  = wsp + 12288;

  // scalar side (identical layout to round-6)
  __shared__ __align__(16) float smem[9472];
  float* t  = smem;           // [16][132]
  float* qb = smem + 2112;    // [16][132] scalar q; later o_s
  float* kb = smem + 4224;    // [16][132] scalar k; later y
  float* vb = smem + 6336;    // [16][132] scalar v; later y2
  float* Bs = smem + 8448;    // [1024] x staging, then bias[4][16][16]
  float* ub = smem;           // [16][260] scalar FFN u (overlays t+qb when dead)
  // MFMA side (round-5 dataflow buffers, fully separate)
  __shared__ __align__(16) float mfm[6912];
  float* Qm = mfm;            // [16][132] MFMA q; later o_m
  float* Km = mfm + 2112;     // [16][132]
  float* Vm = mfm + 4224;     // [16][132]
  float* Um = mfm + 6336;     // [16][36]
  __shared__ __align__(16) unsigned short mb[4352];
  unsigned short* sMh = mb;          // [16][136]
  unsigned short* sMl = mb + 2176;   // [16][136]

  const int tid = threadIdx.x;   // one wave
  const int wi  = blockIdx.x;
  const int lm  = tid & 15;
  const int lg  = tid >> 4;
  const f32x4 zero4 = {0.f,0.f,0.f,0.f};
  uint flags = 0;

  // ========== x staging ==========
  for (int i = tid; i < NHT*ED; i += 64) Bs[i] = x[(size_t)wi*1024 + i];
  __syncthreads();

  // ========== SCALAR stage A (pre-LN) -> t ==========
#pragma unroll
  for (int jj = 0; jj < 2; ++jj){
    const int j = tid + jj*64;
    float acc[NHT];
#pragma unroll
    for (int tok = 0; tok < NHT; ++tok) acc[tok] = 0.f;
    for (int k = 0; k < ED; ++k){
      float w = W_in[(size_t)k*MD + j];
#pragma unroll
      for (int tok = 0; tok < NHT; ++tok) acc[tok] = fmaf(Bs[tok*ED + k], w, acc[tok]);
    }
#pragma unroll
    for (int tok = 0; tok < NHT; ++tok) t[tok*LDT + j] = acc[tok];
  }
  __syncthreads();

  // ========== MFMA stage A + bit0 ==========
  bf8 xh[2], xl[2];
  {
    const float* xp = x + (size_t)wi*1024 + lm*ED + lg*8;
#pragma unroll
    for (int kt = 0; kt < 2; ++kt){
      U8 h, l;
#pragma unroll
      for (int j = 0; j < 8; ++j) splits(xp[kt*32 + j], h.s[j], l.s[j]);
      xh[kt] = h.v; xl[kt] = l.v;
    }
  }
  float tC[8][4];
#pragma unroll
  for (int nt = 0; nt < 8; ++nt){
    f32x4 acc = zero4;
#pragma unroll
    for (int kt = 0; kt < 2; ++kt){
      const float* wp = W_in + (size_t)(kt*32 + lg*8)*MD + nt*16 + lm;
      U8 w;
#pragma unroll
      for (int j = 0; j < 8; ++j) w.s[j] = bf1(wp[(size_t)j*MD]);
      acc = MFMA(xh[kt], w.v, acc, 0,0,0);
      acc = MFMA(xl[kt], w.v, acc, 0,0,0);
    }
#pragma unroll
    for (int r = 0; r < 4; ++r){
      tC[nt][r] = acc[r];
      if (fabsf(acc[r] - t[(lg*4+r)*LDT + nt*16+lm]) > TOL) flags |= 1u;      // bit0
    }
  }

  // ========== LN both + bit1 ==========
  lnC(tC, g_in, b_in, lm);
  ln_rows16(t, g_in, b_in, tid);
  __syncthreads();
#pragma unroll
  for (int nt = 0; nt < 8; ++nt)
#pragma unroll
    for (int r = 0; r < 4; ++r)
      if (fabsf(tC[nt][r] - t[(lg*4+r)*LDT + nt*16+lm]) > TOL) flags |= 2u;   // bit1

  // ========== bounce t -> A-frags + bit2 ==========
#pragma unroll
  for (int nt = 0; nt < 8; ++nt)
#pragma unroll
    for (int r = 0; r < 4; ++r){
      unsigned short h, l; splits(tC[nt][r], h, l);
      sMh[(lg*4+r)*SCRS + nt*16+lm] = h;
      sMl[(lg*4+r)*SCRS + nt*16+lm] = l;
    }
  __syncthreads();
  bf8 tAh[4], tAl[4];
#pragma unroll
  for (int kt = 0; kt < 4; ++kt){
    tAh[kt] = *(const bf8*)(sMh + lm*SCRS + kt*32 + lg*8);
    tAl[kt] = *(const bf8*)(sMl + lm*SCRS + kt*32 + lg*8);
  }
#pragma unroll
  for (int kt = 0; kt < 4; ++kt){
    U8 hh, ll; hh.v = tAh[kt]; ll.v = tAl[kt];
#pragma unroll
    for (int j = 0; j < 8; ++j){
      float rec = bfh2f(hh.s[j]) + bfh2f(ll.s[j]);
      if (fabsf(rec - t[lm*LDT + kt*32 + lg*8 + j]) > TOL) flags |= 4u;       // bit2
    }
  }
  __syncthreads();

  // ========== packw verify (Wq) + bit3 ==========
#pragma unroll
  for (int nt = 0; nt < 8; ++nt)
#pragma unroll
    for (int kt = 0; kt < 4; ++kt){
      U8 f; f.q = pWq[(nt*4+kt)*64 + tid];
#pragma unroll
      for (int j = 0; j < 8; ++j){
        unsigned short exp = bf1(Wq[(size_t)(kt*32 + lg*8 + j)*MD + nt*16 + lm]);
        if (f.s[j] != exp) flags |= 8u;                                        // bit3
      }
    }

  // ========== SCALAR Q,K,V -> qb,kb,vb ==========
#pragma unroll
  for (int jj = 0; jj < 2; ++jj){
    const int j = tid + jj*64;
    float aq[NHT], ak[NHT], av[NHT];
    const float bqj = bq[j], bkj = bk[j], bvj = bv[j];
#pragma unroll
    for (int tok = 0; tok < NHT; ++tok){ aq[tok]=bqj; ak[tok]=bkj; av[tok]=bvj; }
    for (int k = 0; k < MD; ++k){
      float wq = Wq[(size_t)k*MD + j], wk = Wk[(size_t)k*MD + j], wv = Wv[(size_t)k*MD + j];
#pragma unroll
      for (int tok = 0; tok < NHT; ++tok){
        float tv_b = t[tok*LDT + k];
        aq[tok] = fmaf(tv_b, wq, aq[tok]);
        ak[tok] = fmaf(tv_b, wk, ak[tok]);
        av[tok] = fmaf(tv_b, wv, av[tok]);
      }
    }
#pragma unroll
    for (int tok = 0; tok < NHT; ++tok){
      qb[tok*LDT + j] = aq[tok];
      kb[tok*LDT + j] = ak[tok];
      vb[tok*LDT + j] = av[tok];
    }
  }
  __syncthreads();

  // ========== MFMA Q,K,V -> Qm,Km,Vm rows (r5 binding) + bits 4/5/6 ==========
#pragma unroll
  for (int nt = 0; nt < 8; ++nt){
    float bb = bq[nt*16+lm];
    f32x4 acc = {bb,bb,bb,bb};
#pragma unroll
    for (int kt = 0; kt < 4; ++kt){
      U8 bh; bh.q = pWq[(nt*4+kt)*64 + tid];
      acc = MFMA(tAh[kt], bh.v, acc, 0,0,0);
      acc = MFMA(tAl[kt], bh.v, acc, 0,0,0);
    }
#pragma unroll
    for (int r = 0; r < 4; ++r){
      if (fabsf(acc[r] - qb[(lg*4+r)*LDT + nt*16+lm]) > TOL) flags |= 16u;    // bit4
      Qm[(lg*4+r)*LDQ + nt*16+lm] = acc[r];
    }
  }
#pragma unroll
  for (int nt = 0; nt < 8; ++nt){
    float bb = bk[nt*16+lm];
    f32x4 acc = {bb,bb,bb,bb};
#pragma unroll
    for (int kt = 0; kt < 4; ++kt){
      U8 bh; bh.q = pWk[(nt*4+kt)*64 + tid];
      acc = MFMA(tAh[kt], bh.v, acc, 0,0,0);
      acc = MFMA(tAl[kt], bh.v, acc, 0,0,0);
    }
#pragma unroll
    for (int r = 0; r < 4; ++r){
      if (fabsf(acc[r] - kb[(lg*4+r)*LDT + nt*16+lm]) > TOL) flags |= 32u;    // bit5
      Km[(lg*4+r)*LDQ + nt*16+lm] = acc[r];
    }
  }
#pragma unroll
  for (int nt = 0; nt < 8; ++nt){
    float bb = bv[nt*16+lm];
    f32x4 acc = {bb,bb,bb,bb};
#pragma unroll
    for (int kt = 0; kt < 4; ++kt){
      U8 bh; bh.q = pWv[(nt*4+kt)*64 + tid];
      acc = MFMA(tAh[kt], bh.v, acc, 0,0,0);
      acc = MFMA(tAl[kt], bh.v, acc, 0,0,0);
    }
#pragma unroll
    for (int r = 0; r < 4; ++r){
      if (fabsf(acc[r] - vb[(lg*4+r)*LDT + nt*16+lm]) > TOL) flags |= 64u;    // bit6
      Vm[(lg*4+r)*LDQ + nt*16+lm] = acc[r];
    }
  }

  // ========== scalar bias -> Bs ==========
  for (int p = tid; p < NHT*NHT; p += 64){
    float p1 = pos1[(size_t)wi*256 + p];
    float p2 = pos2[(size_t)wi*256 + p];
    float a0=0.f, a1=0.f, a2=0.f, a3=0.f;
#pragma unroll
    for (int i = 0; i < PED; ++i){
      float e = fmaf(p1, W_pe[i], p2 * W_pe[PED+i]);
      float s = silu_f(e);
      a0 = fmaf(s, W_bias[i*4+0], a0);
      a1 = fmaf(s, W_bias[i*4+1], a1);
      a2 = fmaf(s, W_bias[i*4+2], a2);
      a3 = fmaf(s, W_bias[i*4+3], a3);
    }
    Bs[0*256 + p] = a0; Bs[1*256 + p] = a1; Bs[2*256 + p] = a2; Bs[3*256 + p] = a3;
  }
  __syncthreads();

  // ========== scalar attention on SCALAR q/k/v -> o_s (over qb) ==========
  {
    const int h  = tid >> 4;
    const int qi = tid & 15;
    const float* qrow = qb + qi*LDT + h*DH;
    float qf[DH];
#pragma unroll
    for (int d = 0; d < DH; ++d) qf[d] = qrow[d];
    float sc[NHT];
#pragma unroll
    for (int ki = 0; ki < NHT; ++ki){
      const float* krow = kb + ki*LDT + h*DH;
      float dot = 0.f;
#pragma unroll
      for (int d = 0; d < DH; ++d) dot = fmaf(qf[d], krow[d], dot);
      sc[ki] = fmaf(dot, SCALE, Bs[h*256 + qi*16 + ki]);
    }
    float mx = sc[0];
#pragma unroll
    for (int ki = 1; ki < NHT; ++ki) mx = fmaxf(mx, sc[ki]);
    float sum = 0.f;
#pragma unroll
    for (int ki = 0; ki < NHT; ++ki){ sc[ki] = __expf(sc[ki]-mx); sum += sc[ki]; }
    const float inv = 1.f/sum;
    float of[DH];
#pragma unroll
    for (int d = 0; d < DH; ++d) of[d] = 0.f;
#pragma unroll
    for (int ki = 0; ki < NHT; ++ki){
      const float* vrow = vb + ki*LDT + h*DH;
      const float a = sc[ki];
#pragma unroll
      for (int d = 0; d < DH; ++d) of[d] = fmaf(a, vrow[d], of[d]);
    }
    float* orow = qb + qi*LDT + h*DH;
#pragma unroll
    for (int d = 0; d < DH; ++d) orow[d] = of[d]*inv;
  }

  // ========== scalar attention on MFMA q/k/v -> o_m (over Qm), r5 float4 form ==========
  {
    const int h  = tid >> 4;
    const int qi = tid & 15;
    const float* qrow = Qm + qi*LDQ + h*DH;
    float qf[DH];
#pragma unroll
    for (int d = 0; d < DH; d += 4){
      float4 v = *(const float4*)(qrow + d);
      qf[d] = v.x; qf[d+1] = v.y; qf[d+2] = v.z; qf[d+3] = v.w;
    }
    float sc[NHT];
#pragma unroll
    for (int ki = 0; ki < NHT; ++ki){
      const float* krow = Km + ki*LDQ + h*DH;
      float dot = 0.f;
#pragma unroll
      for (int d = 0; d < DH; d += 4){
        float4 kv = *(const float4*)(krow + d);
        dot = fmaf(qf[d], kv.x, dot);   dot = fmaf(qf[d+1], kv.y, dot);
        dot = fmaf(qf[d+2], kv.z, dot); dot = fmaf(qf[d+3], kv.w, dot);
      }
      sc[ki] = fmaf(dot, SCALE, Bs[h*256 + qi*16 + ki]);
    }
    float mx = sc[0];
#pragma unroll
    for (int ki = 1; ki < NHT; ++ki) mx = fmaxf(mx, sc[ki]);
    float sum = 0.f;
#pragma unroll
    for (int ki = 0; ki < NHT; ++ki){ sc[ki] = __expf(sc[ki]-mx); sum += sc[ki]; }
    const float inv = 1.f/sum;
    float of[DH];
#pragma unroll
    for (int d = 0; d < DH; ++d) of[d] = 0.f;
#pragma unroll
    for (int ki = 0; ki < NHT; ++ki){
      const float* vrow = Vm + ki*LDQ + h*DH;
      const float a = sc[ki];
#pragma unroll
      for (int d = 0; d < DH; d += 4){
        float4 vv = *(const float4*)(vrow + d);
        of[d]   = fmaf(a, vv.x, of[d]);   of[d+1] = fmaf(a, vv.y, of[d+1]);
        of[d+2] = fmaf(a, vv.z, of[d+2]); of[d+3] = fmaf(a, vv.w, of[d+3]);
      }
    }
    float* orow = Qm + qi*LDQ + h*DH;
#pragma unroll
    for (int d = 0; d < DH; d += 4){
      float4 o4 = { of[d]*inv, of[d+1]*inv, of[d+2]*inv, of[d+3]*inv };
      *(float4*)(orow + d) = o4;
    }
  }
  __syncthreads();

  // bit7: o_m vs o_s (each lane checks its own slice)
  {
    const int h  = tid >> 4;
    const int qi = tid & 15;
#pragma unroll
    for (int d = 0; d < DH; ++d)
      if (fabsf(Qm[qi*LDQ + h*DH + d] - qb[qi*LDT + h*DH + d]) > TOL) flags |= 128u;
  }

  // ========== SCALAR Wo: kb = t + o_s@Wo + bo (pre-LN) ==========
#pragma unroll
  for (int jj = 0; jj < 2; ++jj){
    const int j = tid + jj*64;
    float acc[NHT];
    const float boj = bo[j];
#pragma unroll
    for (int tok = 0; tok < NHT; ++tok) acc[tok] = boj;
    for (int k = 0; k < MD; ++k){
      float w = Wo[(size_t)k*MD + j];
#pragma unroll
      for (int tok = 0; tok < NHT; ++tok) acc[tok] = fmaf(qb[tok*LDT + k], w, acc[tok]);
    }
#pragma unroll
    for (int tok = 0; tok < NHT; ++tok)
      kb[tok*LDT + j] = acc[tok] + t[tok*LDT + j];
  }
  __syncthreads();

  // ========== MFMA Wo on o_m (r5 float4->split binding) + bit8, LN + bit9 ==========
  bf8 oAh[4], oAl[4];
#pragma unroll
  for (int kt = 0; kt < 4; ++kt){
    const float* orow = Qm + lm*LDQ + kt*32 + lg*8;
    float4 a = *(const float4*)(orow);
    float4 b = *(const float4*)(orow + 4);
    float f[8] = {a.x,a.y,a.z,a.w,b.x,b.y,b.z,b.w};
    U8 h, l;
#pragma unroll
    for (int j = 0; j < 8; ++j) splits(f[j], h.s[j], l.s[j]);
    oAh[kt] = h.v; oAl[kt] = l.v;
  }
#pragma unroll
  for (int nt = 0; nt < 8; ++nt){
    float bb = bo[nt*16+lm];
    f32x4 acc = {bb,bb,bb,bb};
#pragma unroll
    for (int kt = 0; kt < 4; ++kt){
      U8 bh; bh.q = pWo[(nt*4+kt)*64 + tid];
      acc = MFMA(oAh[kt], bh.v, acc, 0,0,0);
      acc = MFMA(oAl[kt], bh.v, acc, 0,0,0);
    }
#pragma unroll
    for (int r = 0; r < 4; ++r){
      float sum = tC[nt][r] + acc[r];
      if (fabsf(sum - kb[(lg*4+r)*LDT + nt*16+lm]) > TOL) flags |= 256u;      // bit8
      tC[nt][r] = sum;
    }
  }
  lnC(tC, g1, b1, lm);
  ln_rows16(kb, g1, b1, tid);
  __syncthreads();
#pragma unroll
  for (int nt = 0; nt < 8; ++nt)
#pragma unroll
    for (int r = 0; r < 4; ++r)
      if (fabsf(tC[nt][r] - kb[(lg*4+r)*LDT + nt*16+lm]) > TOL) flags |= 512u; // bit9

  // ========== y-bounce -> yA frags ==========
#pragma unroll
  for (int nt = 0; nt < 8; ++nt)
#pragma unroll
    for (int r = 0; r < 4; ++r){
      unsigned short h, l; splits(tC[nt][r], h, l);
      sMh[(lg*4+r)*SCRS + nt*16+lm] = h;
      sMl[(lg*4+r)*SCRS + nt*16+lm] = l;
    }
  __syncthreads();
  bf8 yAh[4], yAl[4];
#pragma unroll
  for (int kt = 0; kt < 4; ++kt){
    yAh[kt] = *(const bf8*)(sMh + lm*SCRS + kt*32 + lg*8);
    yAl[kt] = *(const bf8*)(sMl + lm*SCRS + kt*32 + lg*8);
  }
  __syncthreads();

  // ========== SCALAR FFN1 -> ub (overlays t/qb; both dead) ==========
#pragma unroll
  for (int jj = 0; jj < 4; ++jj){
    const int j = tid + jj*64;
    float acc[NHT];
#pragma unroll
    for (int tok = 0; tok < NHT; ++tok) acc[tok] = 0.f;
    for (int k = 0; k < MD; ++k){
      float w = W1[(size_t)k*FFD + j];
#pragma unroll
      for (int tok = 0; tok < NHT; ++tok) acc[tok] = fmaf(kb[tok*LDT + k], w, acc[tok]);
    }
#pragma unroll
    for (int tok = 0; tok < NHT; ++tok) ub[tok*LDU + j] = silu_f(acc[tok]);
  }
  __syncthreads();

  // ========== MFMA FFN interleaved per kt2 (r5 binding via Um) + bit10 ==========
  f32x4 acc2[8];
#pragma unroll
  for (int nt = 0; nt < 8; ++nt) acc2[nt] = zero4;
#pragma unroll
  for (int kt2 = 0; kt2 < 8; ++kt2){
#pragma unroll
    for (int sub = 0; sub < 2; ++sub){
      int nt1 = kt2*2 + sub;
      f32x4 a = zero4;
#pragma unroll
      for (int kt = 0; kt < 4; ++kt){
        U8 bh; bh.q = pW1[(nt1*4+kt)*64 + tid];
        a = MFMA(yAh[kt], bh.v, a, 0,0,0);
        a = MFMA(yAl[kt], bh.v, a, 0,0,0);
      }
#pragma unroll
      for (int r = 0; r < 4; ++r){
        float sv = silu_f(a[r]);
        if (fabsf(sv - ub[(lg*4+r)*LDU + nt1*16+lm]) > TOL) flags |= 1024u;   // bit10
        Um[(lg*4+r)*LDUS + sub*16 + lm] = sv;
      }
    }
    __syncthreads();
    bf8 uh, ul;
    {
      const float* urow = Um + lm*LDUS + lg*8;
      float4 a = *(const float4*)(urow);
      float4 b = *(const float4*)(urow + 4);
      float f[8] = {a.x,a.y,a.z,a.w,b.x,b.y,b.z,b.w};
      U8 h, l;
#pragma unroll
      for (int j = 0; j < 8; ++j) splits(f[j], h.s[j], l.s[j]);
      uh = h.v; ul = l.v;
    }
    __syncthreads();
#pragma unroll
    for (int nt = 0; nt < 8; ++nt){
      U8 bh; bh.q = pW2[(nt*8+kt2)*64 + tid];
      acc2[nt] = MFMA(uh, bh.v, acc2[nt], 0,0,0);
      acc2[nt] = MFMA(ul, bh.v, acc2[nt], 0,0,0);
    }
  }

  // ========== SCALAR FFN2 -> vb = y + ffn (pre-LN) ==========
#pragma unroll
  for (int jj = 0; jj < 2; ++jj){
    const int j = tid + jj*64;
    float acc[NHT];
#pragma unroll
    for (int tok = 0; tok < NHT; ++tok) acc[tok] = 0.f;
    for (int k = 0; k < FFD; ++k){
      float w = W2[(size_t)k*MD + j];
#pragma unroll
      for (int tok = 0; tok < NHT; ++tok) acc[tok] = fmaf(ub[tok*LDU + k], w, acc[tok]);
    }
#pragma unroll
    for (int tok = 0; tok < NHT; ++tok)
      vb[tok*LDT + j] = acc[tok] + kb[tok*LDT + j];
  }
  __syncthreads();

  // ========== bit11 pre-LN, LN both + bit12 ==========
#pragma unroll
  for (int nt = 0; nt < 8; ++nt)
#pragma unroll
    for (int r = 0; r < 4; ++r){
      float sum = tC[nt][r] + acc2[nt][r];
      if (fabsf(sum - vb[(lg*4+r)*LDT + nt*16+lm]) > TOL) flags |= 2048u;     // bit11
      tC[nt][r] = sum;
    }
  lnC(tC, g2, b2, lm);
  ln_rows16(vb, g2, b2, tid);
  __syncthreads();
#pragma unroll
  for (int nt = 0; nt < 8; ++nt)
#pragma unroll
    for (int r = 0; r < 4; ++r)
      if (fabsf(tC[nt][r] - vb[(lg*4+r)*LDT + nt*16+lm]) > TOL) flags |= 4096u; // bit12

  // ========== store the MFMA-chain result (round-5's exact store) ==========
  float* op = out + (size_t)wi*(NHT*MD);
#pragma unroll
  for (int nt = 0; nt < 8; ++nt)
#pragma unroll
    for (int r = 0; r < 4; ++r)
      op[(lg*4+r)*MD + nt*16+lm] = tC[nt][r];

  // flags: OR-reduce, encode into THIS window's out region (no cross-block race)
#pragma unroll
  for (int m = 1; m < 64; m <<= 1) flags |= (uint)__shfl_xor((int)flags, m);
  if (tid == 0 && flags != 0)
    atomicMax((int*)(out + (size_t)wi*(NHT*MD)), __float_as_int(512.0f * (float)flags));
}

extern "C" void kernel_launch(void* const* d_in, const int* in_sizes, int n_in,
                              void* d_out, int out_size, void* d_ws, size_t ws_size,
                              hipStream_t stream) {
  const float* x     = (const float*)d_in[0];
  const float* pos1  = (const float*)d_in[1];
  const float* pos2  = (const float*)d_in[2];
  const float* W_in  = (const float*)d_in[3];
  const float* g_in  = (const float*)d_in[4];
  const float* b_in  = (const float*)d_in[5];
  const float* W_pe  = (const float*)d_in[6];
  const float* W_bias= (const float*)d_in[7];
  const float* Wq    = (const float*)d_in[8];
  const float* bq    = (const float*)d_in[9];
  const float* Wk    = (const float*)d_in[10];
  const float* bk    = (const float*)d_in[11];
  const float* Wv    = (const float*)d_in[12];
  const float* bv    = (const float*)d_in[13];
  const float* Wo    = (const float*)d_in[14];
  const float* bo    = (const float*)d_in[15];
  const float* W1    = (const float*)d_in[16];
  const float* W2    = (const float*)d_in[17];
  const float* g1    = (const float*)d_in[18];
  const float* b1    = (const float*)d_in[19];
  const float* g2    = (const float*)d_in[20];
  const float* b2    = (const float*)d_in[21];
  float* out = (float*)d_out;
  uint4* ws  = (uint4*)d_ws;   // 16384 * 16B = 262144 B

  packw<<<64, 256, 0, stream>>>(Wq, Wk, Wv, Wo, W1, W2, ws);

  const int nwin = in_sizes[0] / (NHT * ED);   // 16384
  nha_diag2<<<nwin, 64, 0, stream>>>(x, pos1, pos2, W_in, g_in, b_in, W_pe, W_bias,
                                     Wq, bq, Wk, bk, Wv, bv, Wo, bo,
                                     W1, W2, g1, b1, g2, b2, ws, out);
}

// Round 8
// 508.066 us; speedup vs baseline: 47.7113x; 47.7113x over previous
//
#include <hip/hip_runtime.h>
#include <hip/hip_bf16.h>
#include <math.h>

// B=4, N=4096 -> 16384 windows of NHT=16 tokens, MD=128
#define NHT 16
#define MD 128
#define FFD 256
#define NHEAD 4
#define DH 32
#define PED 32
#define ED 64
#define SCALE 0.17677669529663687f
#define LDQ 132      // float stride, natural Q/K/V/o rows
#define LDUS 36      // float stride, FFN u rows
#define SCRS 136     // short stride, bounce rows

typedef __attribute__((ext_vector_type(8))) short bf8;
typedef __attribute__((ext_vector_type(4))) float f32x4;
union U8 { bf8 v; unsigned short s[8]; uint u[4]; uint4 q; };

#define MFMA __builtin_amdgcn_mfma_f32_16x16x32_bf16

__device__ __forceinline__ unsigned short bf1(float a){
  __hip_bfloat16 h = __float2bfloat16(a);
  return *reinterpret_cast<unsigned short*>(&h);
}
__device__ __forceinline__ void splits(float f, unsigned short &h, unsigned short &l){
  __hip_bfloat16 hb = __float2bfloat16(f);
  h = *reinterpret_cast<unsigned short*>(&hb);
  float r = f - __bfloat162float(hb);
  __hip_bfloat16 lb = __float2bfloat16(r);
  l = *reinterpret_cast<unsigned short*>(&lb);
}
__device__ __forceinline__ float silu_f(float x){ return x / (1.f + __expf(-x)); }

// butterfly LN on MFMA C-layout tile (lane: rows lg*4+r, cols nt*16+lm)
__device__ __forceinline__ void lnC(float (&C)[8][4], const float* __restrict__ g,
                                    const float* __restrict__ b, int lm){
#pragma unroll
  for (int r = 0; r < 4; ++r){
    float s = 0.f, ss = 0.f;
#pragma unroll
    for (int nt = 0; nt < 8; ++nt){ s += C[nt][r]; ss = fmaf(C[nt][r], C[nt][r], ss); }
#pragma unroll
    for (int m = 1; m < 16; m <<= 1){ s += __shfl_xor(s, m); ss += __shfl_xor(ss, m); }
    float mean = s * (1.f/128.f);
    float var  = ss * (1.f/128.f) - mean*mean;
    float rs   = rsqrtf(var + 1e-5f);
#pragma unroll
    for (int nt = 0; nt < 8; ++nt)
      C[nt][r] = fmaf((C[nt][r] - mean) * rs, g[nt*16+lm], b[nt*16+lm]);
  }
}

// ---- weight pre-pack: fp32 [K][N] -> bf16 B-frag order, hi only; 256 KiB exact ----
// unit u = (nt*KT+kt)*64+lane holds 8 bf16: W[kt*32+(lane>>4)*8 + j][nt*16+(lane&15)]
__global__ __launch_bounds__(256)
void packw(const float* __restrict__ Wq, const float* __restrict__ Wk,
           const float* __restrict__ Wv, const float* __restrict__ Wo,
           const float* __restrict__ W1, const float* __restrict__ W2,
           uint4* __restrict__ ws){
  int id = blockIdx.x * 256 + threadIdx.x;   // 16384 total
  const float* W; int KT, N, u; uint4* dst;
  if      (id < 2048) { W = Wq;  KT = 4; N = 128; dst = ws;         u = id;         }
  else if (id < 4096) { W = Wk;  KT = 4; N = 128; dst = ws + 2048;  u = id - 2048;  }
  else if (id < 6144) { W = Wv;  KT = 4; N = 128; dst = ws + 4096;  u = id - 4096;  }
  else if (id < 8192) { W = Wo;  KT = 4; N = 128; dst = ws + 6144;  u = id - 6144;  }
  else if (id < 12288){ W = W1;  KT = 4; N = 256; dst = ws + 8192;  u = id - 8192;  }
  else                { W = W2;  KT = 8; N = 128; dst = ws + 12288; u = id - 12288; }
  int lane = u & 63, tile = u >> 6;
  int kt = tile % KT, nt = tile / KT;
  int kr  = kt*32 + ((lane >> 4) << 3);
  int col = nt*16 + (lane & 15);
  const float* p = W + (size_t)kr * N + col;
  U8 hi;
#pragma unroll
  for (int j = 0; j < 8; ++j) hi.s[j] = bf1(p[(size_t)j * N]);
  dst[u] = hi.q;
}

// ---- round-7's verified MFMA chain, stripped of the scalar pipeline.
// Dedicated non-aliased LDS buffers (the only code-level difference from
// round-5, which failed; round-7 with these buffers passed at 0.031).
__global__ __launch_bounds__(64)
void nha_mfma(const float* __restrict__ x, const float* __restrict__ pos1,
              const float* __restrict__ pos2,
              const float* __restrict__ W_in,
              const float* __restrict__ g_in, const float* __restrict__ b_in,
              const float* __restrict__ W_pe, const float* __restrict__ W_bias,
              const float* __restrict__ bq, const float* __restrict__ bk,
              const float* __restrict__ bv, const float* __restrict__ bo,
              const float* __restrict__ g1, const float* __restrict__ b1,
              const float* __restrict__ g2, const float* __restrict__ b2,
              const uint4* __restrict__ wsp, float* __restrict__ out)
{
  const uint4* pWq  = wsp;
  const uint4* pWk  = wsp + 2048;
  const uint4* pWv  = wsp + 4096;
  const uint4* pWo  = wsp + 6144;
  const uint4* pW1  = wsp + 8192;
  const uint4* pW2  = wsp + 12288;

  __shared__ __align__(16) float Qm[NHT*LDQ];            // q rows; later o rows
  __shared__ __align__(16) float Km[NHT*LDQ];
  __shared__ __align__(16) float Vm[NHT*LDQ];
  __shared__ __align__(16) float Um[NHT*LDUS];
  __shared__ __align__(16) float Bsm[NHEAD*NHT*NHT];
  __shared__ __align__(16) unsigned short sMh[NHT*SCRS];
  __shared__ __align__(16) unsigned short sMl[NHT*SCRS];

  const int tid = threadIdx.x;   // one wave per block/window
  const int wi  = blockIdx.x;
  const int lm  = tid & 15;
  const int lg  = tid >> 4;
  const f32x4 zero4 = {0.f,0.f,0.f,0.f};

  // ========== Stage A: t = LN(x @ W_in); W_in B-frags straight from fp32 ==========
  bf8 xh[2], xl[2];
  {
    const float* xp = x + (size_t)wi*1024 + lm*ED + lg*8;
#pragma unroll
    for (int kt = 0; kt < 2; ++kt){
      U8 h, l;
#pragma unroll
      for (int j = 0; j < 8; ++j) splits(xp[kt*32 + j], h.s[j], l.s[j]);
      xh[kt] = h.v; xl[kt] = l.v;
    }
  }
  float tC[8][4];
#pragma unroll
  for (int nt = 0; nt < 8; ++nt){
    f32x4 acc = zero4;
#pragma unroll
    for (int kt = 0; kt < 2; ++kt){
      const float* wp = W_in + (size_t)(kt*32 + lg*8)*MD + nt*16 + lm;
      U8 w;
#pragma unroll
      for (int j = 0; j < 8; ++j) w.s[j] = bf1(wp[(size_t)j*MD]);
      acc = MFMA(xh[kt], w.v, acc, 0,0,0);
      acc = MFMA(xl[kt], w.v, acc, 0,0,0);
    }
#pragma unroll
    for (int r = 0; r < 4; ++r) tC[nt][r] = acc[r];
  }
  lnC(tC, g_in, b_in, lm);

  // ========== bounce t -> hi/lo A-frags ==========
#pragma unroll
  for (int nt = 0; nt < 8; ++nt)
#pragma unroll
    for (int r = 0; r < 4; ++r){
      unsigned short h, l; splits(tC[nt][r], h, l);
      sMh[(lg*4+r)*SCRS + nt*16+lm] = h;
      sMl[(lg*4+r)*SCRS + nt*16+lm] = l;
    }
  __syncthreads();
  bf8 tAh[4], tAl[4];
#pragma unroll
  for (int kt = 0; kt < 4; ++kt){
    tAh[kt] = *(const bf8*)(sMh + lm*SCRS + kt*32 + lg*8);
    tAl[kt] = *(const bf8*)(sMl + lm*SCRS + kt*32 + lg*8);
  }
  __syncthreads();

  // ========== Q,K,V = t@W + b -> natural fp32 rows ==========
#pragma unroll
  for (int nt = 0; nt < 8; ++nt){
    float bb = bq[nt*16+lm];
    f32x4 acc = {bb,bb,bb,bb};
#pragma unroll
    for (int kt = 0; kt < 4; ++kt){
      U8 bh; bh.q = pWq[(nt*4+kt)*64 + tid];
      acc = MFMA(tAh[kt], bh.v, acc, 0,0,0);
      acc = MFMA(tAl[kt], bh.v, acc, 0,0,0);
    }
#pragma unroll
    for (int r = 0; r < 4; ++r) Qm[(lg*4+r)*LDQ + nt*16+lm] = acc[r];
  }
#pragma unroll
  for (int nt = 0; nt < 8; ++nt){
    float bb = bk[nt*16+lm];
    f32x4 acc = {bb,bb,bb,bb};
#pragma unroll
    for (int kt = 0; kt < 4; ++kt){
      U8 bh; bh.q = pWk[(nt*4+kt)*64 + tid];
      acc = MFMA(tAh[kt], bh.v, acc, 0,0,0);
      acc = MFMA(tAl[kt], bh.v, acc, 0,0,0);
    }
#pragma unroll
    for (int r = 0; r < 4; ++r) Km[(lg*4+r)*LDQ + nt*16+lm] = acc[r];
  }
#pragma unroll
  for (int nt = 0; nt < 8; ++nt){
    float bb = bv[nt*16+lm];
    f32x4 acc = {bb,bb,bb,bb};
#pragma unroll
    for (int kt = 0; kt < 4; ++kt){
      U8 bh; bh.q = pWv[(nt*4+kt)*64 + tid];
      acc = MFMA(tAh[kt], bh.v, acc, 0,0,0);
      acc = MFMA(tAl[kt], bh.v, acc, 0,0,0);
    }
#pragma unroll
    for (int r = 0; r < 4; ++r) Vm[(lg*4+r)*LDQ + nt*16+lm] = acc[r];
  }

  // ========== rel-pos bias -> Bsm[h][qi][ki] (fp32 exact) ==========
  for (int p = tid; p < NHT*NHT; p += 64){
    float p1 = pos1[(size_t)wi*256 + p];
    float p2 = pos2[(size_t)wi*256 + p];
    float a0=0.f, a1=0.f, a2=0.f, a3=0.f;
#pragma unroll
    for (int i = 0; i < PED; ++i){
      float e = fmaf(p1, W_pe[i], p2 * W_pe[PED+i]);
      float s = silu_f(e);
      a0 = fmaf(s, W_bias[i*4+0], a0);
      a1 = fmaf(s, W_bias[i*4+1], a1);
      a2 = fmaf(s, W_bias[i*4+2], a2);
      a3 = fmaf(s, W_bias[i*4+3], a3);
    }
    Bsm[0*256 + p] = a0; Bsm[1*256 + p] = a1; Bsm[2*256 + p] = a2; Bsm[3*256 + p] = a3;
  }
  __syncthreads();

  // ========== attention: scalar fp32, lane = (head, q-row); o over Qm ==========
  {
    const int h  = tid >> 4;
    const int qi = tid & 15;
    const float* qrow = Qm + qi*LDQ + h*DH;
    float qf[DH];
#pragma unroll
    for (int d = 0; d < DH; d += 4){
      float4 v = *(const float4*)(qrow + d);
      qf[d] = v.x; qf[d+1] = v.y; qf[d+2] = v.z; qf[d+3] = v.w;
    }
    float sc[NHT];
#pragma unroll
    for (int ki = 0; ki < NHT; ++ki){
      const float* krow = Km + ki*LDQ + h*DH;
      float dot = 0.f;
#pragma unroll
      for (int d = 0; d < DH; d += 4){
        float4 kv = *(const float4*)(krow + d);
        dot = fmaf(qf[d], kv.x, dot);   dot = fmaf(qf[d+1], kv.y, dot);
        dot = fmaf(qf[d+2], kv.z, dot); dot = fmaf(qf[d+3], kv.w, dot);
      }
      sc[ki] = fmaf(dot, SCALE, Bsm[h*256 + qi*16 + ki]);
    }
    float mx = sc[0];
#pragma unroll
    for (int ki = 1; ki < NHT; ++ki) mx = fmaxf(mx, sc[ki]);
    float sum = 0.f;
#pragma unroll
    for (int ki = 0; ki < NHT; ++ki){ sc[ki] = __expf(sc[ki]-mx); sum += sc[ki]; }
    const float inv = 1.f/sum;
    float of[DH];
#pragma unroll
    for (int d = 0; d < DH; ++d) of[d] = 0.f;
#pragma unroll
    for (int ki = 0; ki < NHT; ++ki){
      const float* vrow = Vm + ki*LDQ + h*DH;
      const float a = sc[ki];
#pragma unroll
      for (int d = 0; d < DH; d += 4){
        float4 vv = *(const float4*)(vrow + d);
        of[d]   = fmaf(a, vv.x, of[d]);   of[d+1] = fmaf(a, vv.y, of[d+1]);
        of[d+2] = fmaf(a, vv.z, of[d+2]); of[d+3] = fmaf(a, vv.w, of[d+3]);
      }
    }
    float* orow = Qm + qi*LDQ + h*DH;   // lane-exclusive slice
#pragma unroll
    for (int d = 0; d < DH; d += 4){
      float4 o4 = { of[d]*inv, of[d+1]*inv, of[d+2]*inv, of[d+3]*inv };
      *(float4*)(orow + d) = o4;
    }
  }
  __syncthreads();

  // ========== att_out = o@Wo + bo, residual, LN(g1,b1) ==========
  bf8 oAh[4], oAl[4];
#pragma unroll
  for (int kt = 0; kt < 4; ++kt){
    const float* orow = Qm + lm*LDQ + kt*32 + lg*8;
    float4 a = *(const float4*)(orow);
    float4 b = *(const float4*)(orow + 4);
    float f[8] = {a.x,a.y,a.z,a.w,b.x,b.y,b.z,b.w};
    U8 h, l;
#pragma unroll
    for (int j = 0; j < 8; ++j) splits(f[j], h.s[j], l.s[j]);
    oAh[kt] = h.v; oAl[kt] = l.v;
  }
#pragma unroll
  for (int nt = 0; nt < 8; ++nt){
    float bb = bo[nt*16+lm];
    f32x4 acc = {bb,bb,bb,bb};
#pragma unroll
    for (int kt = 0; kt < 4; ++kt){
      U8 bh; bh.q = pWo[(nt*4+kt)*64 + tid];
      acc = MFMA(oAh[kt], bh.v, acc, 0,0,0);
      acc = MFMA(oAl[kt], bh.v, acc, 0,0,0);
    }
#pragma unroll
    for (int r = 0; r < 4; ++r) tC[nt][r] += acc[r];   // y = t + att_out
  }
  lnC(tC, g1, b1, lm);
  __syncthreads();

  // ========== bounce y -> hi/lo A-frags ==========
#pragma unroll
  for (int nt = 0; nt < 8; ++nt)
#pragma unroll
    for (int r = 0; r < 4; ++r){
      unsigned short h, l; splits(tC[nt][r], h, l);
      sMh[(lg*4+r)*SCRS + nt*16+lm] = h;
      sMl[(lg*4+r)*SCRS + nt*16+lm] = l;
    }
  __syncthreads();
  bf8 yAh[4], yAl[4];
#pragma unroll
  for (int kt = 0; kt < 4; ++kt){
    yAh[kt] = *(const bf8*)(sMh + lm*SCRS + kt*32 + lg*8);
    yAl[kt] = *(const bf8*)(sMl + lm*SCRS + kt*32 + lg*8);
  }
  __syncthreads();

  // ========== FFN1 (silu) interleaved with FFN2 accumulation ==========
  f32x4 acc2[8];
#pragma unroll
  for (int nt = 0; nt < 8; ++nt) acc2[nt] = zero4;
#pragma unroll
  for (int kt2 = 0; kt2 < 8; ++kt2){
#pragma unroll
    for (int sub = 0; sub < 2; ++sub){
      int nt1 = kt2*2 + sub;
      f32x4 a = zero4;
#pragma unroll
      for (int kt = 0; kt < 4; ++kt){
        U8 bh; bh.q = pW1[(nt1*4+kt)*64 + tid];
        a = MFMA(yAh[kt], bh.v, a, 0,0,0);
        a = MFMA(yAl[kt], bh.v, a, 0,0,0);
      }
#pragma unroll
      for (int r = 0; r < 4; ++r)
        Um[(lg*4+r)*LDUS + sub*16 + lm] = silu_f(a[r]);
    }
    __syncthreads();
    bf8 uh, ul;
    {
      const float* urow = Um + lm*LDUS + lg*8;
      float4 a = *(const float4*)(urow);
      float4 b = *(const float4*)(urow + 4);
      float f[8] = {a.x,a.y,a.z,a.w,b.x,b.y,b.z,b.w};
      U8 h, l;
#pragma unroll
      for (int j = 0; j < 8; ++j) splits(f[j], h.s[j], l.s[j]);
      uh = h.v; ul = l.v;
    }
    __syncthreads();
#pragma unroll
    for (int nt = 0; nt < 8; ++nt){
      U8 bh; bh.q = pW2[(nt*8+kt2)*64 + tid];
      acc2[nt] = MFMA(uh, bh.v, acc2[nt], 0,0,0);
      acc2[nt] = MFMA(ul, bh.v, acc2[nt], 0,0,0);
    }
  }

  // ========== residual2, LN(g2,b2), store ==========
#pragma unroll
  for (int nt = 0; nt < 8; ++nt)
#pragma unroll
    for (int r = 0; r < 4; ++r) tC[nt][r] += acc2[nt][r];
  lnC(tC, g2, b2, lm);

  float* op = out + (size_t)wi*(NHT*MD);
#pragma unroll
  for (int nt = 0; nt < 8; ++nt)
#pragma unroll
    for (int r = 0; r < 4; ++r)
      op[(lg*4+r)*MD + nt*16+lm] = tC[nt][r];
}

extern "C" void kernel_launch(void* const* d_in, const int* in_sizes, int n_in,
                              void* d_out, int out_size, void* d_ws, size_t ws_size,
                              hipStream_t stream) {
  const float* x     = (const float*)d_in[0];
  const float* pos1  = (const float*)d_in[1];
  const float* pos2  = (const float*)d_in[2];
  const float* W_in  = (const float*)d_in[3];
  const float* g_in  = (const float*)d_in[4];
  const float* b_in  = (const float*)d_in[5];
  const float* W_pe  = (const float*)d_in[6];
  const float* W_bias= (const float*)d_in[7];
  const float* Wq    = (const float*)d_in[8];
  const float* bq    = (const float*)d_in[9];
  const float* Wk    = (const float*)d_in[10];
  const float* bk    = (const float*)d_in[11];
  const float* Wv    = (const float*)d_in[12];
  const float* bv    = (const float*)d_in[13];
  const float* Wo    = (const float*)d_in[14];
  const float* bo    = (const float*)d_in[15];
  const float* W1    = (const float*)d_in[16];
  const float* W2    = (const float*)d_in[17];
  const float* g1    = (const float*)d_in[18];
  const float* b1    = (const float*)d_in[19];
  const float* g2    = (const float*)d_in[20];
  const float* b2    = (const float*)d_in[21];
  float* out = (float*)d_out;
  uint4* ws  = (uint4*)d_ws;   // 16384 * 16B = 262144 B exactly

  packw<<<64, 256, 0, stream>>>(Wq, Wk, Wv, Wo, W1, W2, ws);

  const int nwin = in_sizes[0] / (NHT * ED);   // 16384
  nha_mfma<<<nwin, 64, 0, stream>>>(x, pos1, pos2, W_in, g_in, b_in, W_pe, W_bias,
                                    bq, bk, bv, bo, g1, b1, g2, b2, ws, out);
}